// Round 9
// baseline (184.737 us; speedup 1.0000x reference)
//
#include <hip/hip_runtime.h>

#define BATCH 1024
#define SEQ 256
#define HIDDEN 128
#define VOCAB 60
#define WPB 4               // waves per block; 1 batch row per wave, no interaction

typedef _Float16 f16x8 __attribute__((ext_vector_type(8)));
typedef float f32x4 __attribute__((ext_vector_type(4)));

__device__ __forceinline__ float fast_tanh(float x) {
    // tanh(x) = 1 - 2/(exp(2x)+1); exp(2x)=exp2(x*2*log2e). Branch-free, exact +-1 tails.
    float e = __builtin_amdgcn_exp2f(x * 2.8853900817779268f);
    return __builtin_fmaf(-2.0f, __builtin_amdgcn_rcpf(e + 1.0f), 1.0f);
}

__device__ __forceinline__ f32x4 MF(f16x8 a, f16x8 b, f32x4 c) {
    return __builtin_amdgcn_mfma_f32_16x16x32_f16(a, b, c, 0, 0, 0);
}

// embW[v][i] = sum_j emb[v][j] * W_ih[i][j]  (fp32-exact input-projection table)
__global__ void rnn_prep_embw(const float* __restrict__ emb,
                              const float* __restrict__ W_ih,
                              float* __restrict__ embW) {
    const int v = blockIdx.x;
    const int i = threadIdx.x;
    __shared__ __align__(16) float e[HIDDEN];
    e[i] = emb[v * HIDDEN + i];
    __syncthreads();
    const float4* wrow = (const float4*)(W_ih + i * HIDDEN);
    const float4* e4 = (const float4*)e;
    float a0 = 0.f, a1 = 0.f, a2 = 0.f, a3 = 0.f;
#pragma unroll
    for (int j = 0; j < HIDDEN / 4; ++j) {
        float4 w = wrow[j];
        float4 h = e4[j];
        a0 += w.x * h.x; a1 += w.y * h.y; a2 += w.z * h.z; a3 += w.w * h.w;
    }
    embW[v * HIDDEN + i] = (a0 + a1) + (a2 + a3);
}

// R24: WAVE-LOCAL recurrence. 256 blocks x 256 threads; each of the 4 waves
// owns ONE batch row end-to-end -- h never leaves the wave, NO barriers
// anywhere in the main loop. This deletes both terms of the calibrated step
// model (DS-burst 48 ops -> 5; cross-wave barrier tail -> in-wave DS bounce).
// Per step: z = W_hh*h via 32 MFMAs (8 mgrp x 4 kchunk; W_hh in 128 VGPRs;
// the 16-wide n-dim aliases the single row -- redundant MFMA work is free at
// 10% MfmaUtil). D-layout: value z[m] (m = mg*16 + q*4 + reg) lives at lanes
// (q = (m&15)>>2, any n), reg-indexed. Ownership: lane (q,n) owns the two
// values mg = n>>1, reg = 2*(n&1)+{0,1} -> m_own = (n>>1)*16+q*4+(n&1)*2
// (bijective: 64 lanes x 2 = 128). Extraction via compile-time unrolled
// selects (no runtime vector indexing -> no scratch). Seed = per-lane 8B
// float2 from L2-resident embW, prefetched 1 step ahead (token 2 ahead);
// with zero barriers the prefetch is NEVER drained (R18/R19's failure mode
// is structurally absent). h round-trip: 1 ds_write_b32 -> 4 broadcast
// ds_read_b128, same-wave in-order DS, lgkm-tracked by the compiler.
__global__ void __launch_bounds__(256, 1)
rnn_wavelocal(const int* __restrict__ x, const int* __restrict__ lengths,
              const float* __restrict__ embW, const float* __restrict__ W_hh,
              const float* __restrict__ W_fc, const float* __restrict__ b_fc,
              float* __restrict__ out) {
    const int tid = threadIdx.x;
    const int wave = tid >> 6;
    const int lane = tid & 63;
    const int q = lane >> 4;        // 0..3
    const int n = lane & 15;        // 0..15 (all alias the same batch row)
    const int mg_own = n >> 1;      // owned m-group
    const int half = n & 1;         // owned reg pair within the group
    const int m_own = mg_own * 16 + q * 4 + half * 2;   // owns m_own, m_own+1
    const int row = blockIdx.x * WPB + wave;

    __shared__ __align__(16) _Float16 hbuf[WPB][2][HIDDEN];  // 2048 B
    __shared__ __align__(16) float hf[WPB][HIDDEN];          // 2048 B

    // A-frags: Wf[mg][kc][j] = W_hh[mg*16 + n][kc*32 + q*8 + j]
    // (A-layout: m = lane&15, k = (lane>>4)*8 + j -- same pattern the
    // champion verified). 32 frags = 128 VGPRs, loop-invariant.
    f16x8 Wf[8][4];
    {
        const float* wr = W_hh + n * HIDDEN + q * 8;
#pragma unroll
        for (int mg = 0; mg < 8; ++mg) {
#pragma unroll
            for (int kc = 0; kc < 4; ++kc) {
                const float* p = wr + mg * 16 * HIDDEN + kc * 32;
                float4 w0 = *(const float4*)p;
                float4 w1 = *(const float4*)(p + 4);
                f16x8 f;
                f[0] = (_Float16)w0.x; f[1] = (_Float16)w0.y;
                f[2] = (_Float16)w0.z; f[3] = (_Float16)w0.w;
                f[4] = (_Float16)w1.x; f[5] = (_Float16)w1.y;
                f[6] = (_Float16)w1.z; f[7] = (_Float16)w1.w;
                Wf[mg][kc] = f;
            }
        }
    }

    // h0 = 0: each lane zeroes its owned b32 slot of buffer 0.
    *(unsigned int*)&hbuf[wave][0][m_own] = 0u;

    const int mylen = lengths[row];        // wave-uniform
    const int* xrow = x + row * SEQ;

    // Seed pipeline: token t+1 in flight 1 step, seed t+1 in flight 1 step.
    int tok0 = xrow[0];
    int tok_nxt = xrow[1];
    float2 sd_cur = *(const float2*)(embW + tok0 * HIDDEN + m_own);

    float ta = 0.f, tb = 0.f;
    int cur = 0;

    for (int t = 0; t < mylen; ++t) {
        // Prefetch seed(t+1) and token(t+2). No barriers exist, so these
        // coast on vmcnt until consumed next step (~500 cyc slack).
        float2 sd_nxt = *(const float2*)(embW + tok_nxt * HIDDEN + m_own);
        int tok_n2 = xrow[(t + 2 < SEQ) ? t + 2 : SEQ - 1];

        // B-frags: h[k], k = kc*32 + q*8 + j. 4 distinct addrs, 16-way
        // broadcast -> conflict-free.
        const _Float16* hb = &hbuf[wave][cur][q * 8];
        f16x8 H0 = *(const f16x8*)(hb + 0);
        f16x8 H1 = *(const f16x8*)(hb + 32);
        f16x8 H2 = *(const f16x8*)(hb + 64);
        f16x8 H3 = *(const f16x8*)(hb + 96);

        const f32x4 Z = {0.f, 0.f, 0.f, 0.f};
        f32x4 acc[8];
#pragma unroll
        for (int mg = 0; mg < 8; ++mg) {      // 8 independent 4-deep chains
            acc[mg] = MF(Wf[mg][0], H0, Z);
            acc[mg] = MF(Wf[mg][1], H1, acc[mg]);
            acc[mg] = MF(Wf[mg][2], H2, acc[mg]);
            acc[mg] = MF(Wf[mg][3], H3, acc[mg]);
        }

        // Extract the two owned z values (compile-time acc indices only).
        float za = 0.f, zb = 0.f;
#pragma unroll
        for (int mg = 0; mg < 8; ++mg) {
            za = (mg_own == mg) ? (half ? acc[mg][2] : acc[mg][0]) : za;
            zb = (mg_own == mg) ? (half ? acc[mg][3] : acc[mg][1]) : zb;
        }

        za += sd_cur.x;
        zb += sd_cur.y;
        ta = fast_tanh(za);
        tb = fast_tanh(zb);

        unsigned int pk = __builtin_bit_cast(unsigned int,
                              __builtin_amdgcn_cvt_pkrtz(ta, tb));
        const int nxt = cur ^ 1;
        *(unsigned int*)&hbuf[wave][nxt][m_own] = pk;   // all 64 lanes, bijective

        sd_cur = sd_nxt;
        tok_nxt = tok_n2;
        cur = nxt;
    }
    // Loop ends at t = mylen-1, so (ta, tb) ARE h[len-1] -- no capture logic.

    // FC epilogue, wave-local (own row only; same-wave LDS, lgkm-ordered).
    *(float2*)&hf[wave][m_own] = make_float2(ta, tb);
    const int c = lane;
    if (c < VOCAB) {
        const float4* hv = (const float4*)hf[wave];
        const float4* wf = (const float4*)(W_fc + c * HIDDEN);
        float a0 = 0.f, a1 = 0.f, a2 = 0.f, a3 = 0.f;
#pragma unroll
        for (int j = 0; j < HIDDEN / 4; ++j) {
            float4 h = hv[j];     // broadcast reads
            float4 w = wf[j];
            a0 += h.x * w.x; a1 += h.y * w.y; a2 += h.z * w.z; a3 += h.w * w.w;
        }
        out[row * VOCAB + c] = (a0 + a1) + (a2 + a3) + b_fc[c];
    }
}

extern "C" void kernel_launch(void* const* d_in, const int* in_sizes, int n_in,
                              void* d_out, int out_size, void* d_ws, size_t ws_size,
                              hipStream_t stream) {
    const int* x = (const int*)d_in[0];          // [B, T] int32
    const int* lengths = (const int*)d_in[1];    // [B] int32
    const float* emb = (const float*)d_in[2];    // [V, H]
    const float* W_ih = (const float*)d_in[3];   // [H, H]
    const float* W_hh = (const float*)d_in[4];   // [H, H]
    const float* W_fc = (const float*)d_in[5];   // [V, H]
    const float* b_fc = (const float*)d_in[6];   // [V]
    float* out = (float*)d_out;                  // [B, V]

    float* embW = (float*)d_ws;                  // VOCAB*HIDDEN floats (30 KB)

    rnn_prep_embw<<<VOCAB, HIDDEN, 0, stream>>>(emb, W_ih, embW);
    rnn_wavelocal<<<BATCH / WPB, 256, 0, stream>>>(x, lengths, embW, W_hh,
                                                   W_fc, b_fc, out);
}

// Round 10
// 160.518 us; speedup vs baseline: 1.1509x; 1.1509x over previous
//
#include <hip/hip_runtime.h>
#include <hip/hip_bf16.h>

#define BATCH 1024
#define SEQ 256
#define HIDDEN 128
#define VOCAB 60
#define ROWS 4             // real batch rows per block (MFMA n-dim aliased 4x)
#define CHUNK 16           // ring-buffer depth in time steps
#define ASTRIDE 144        // f16 per h row: 72 dw == 8 mod 32 -> max 2-way (free)
#define RSTR 136           // f32 per ring row: 136 == 8 mod 32 -> conflict-free b128 pattern

typedef _Float16 f16x8 __attribute__((ext_vector_type(8)));
typedef _Float16 f16x4 __attribute__((ext_vector_type(4)));
typedef float f32x4 __attribute__((ext_vector_type(4)));

__device__ __forceinline__ float fast_tanh(float x) {
    // tanh(x) = 1 - 2/(exp(2x)+1); exp(2x)=exp2(x*2*log2e). Branch-free, exact +-1 tails.
    float e = __builtin_amdgcn_exp2f(x * 2.8853900817779268f);
    return __builtin_fmaf(-2.0f, __builtin_amdgcn_rcpf(e + 1.0f), 1.0f);
}

// embW[v][i] = sum_j emb[v][j] * W_ih[i][j]  (fp32-exact input-projection table)
__global__ void rnn_prep_embw(const float* __restrict__ emb,
                              const float* __restrict__ W_ih,
                              float* __restrict__ embW) {
    const int v = blockIdx.x;
    const int i = threadIdx.x;
    __shared__ __align__(16) float e[HIDDEN];
    e[i] = emb[v * HIDDEN + i];
    __syncthreads();
    const float4* wrow = (const float4*)(W_ih + i * HIDDEN);
    const float4* e4 = (const float4*)e;
    float a0 = 0.f, a1 = 0.f, a2 = 0.f, a3 = 0.f;
#pragma unroll
    for (int j = 0; j < HIDDEN / 4; ++j) {
        float4 w = wrow[j];
        float4 h = e4[j];
        a0 += w.x * h.x; a1 += w.y * h.y; a2 += w.z * h.z; a3 += w.w * h.w;
    }
    embW[v * HIDDEN + i] = (a0 + a1) + (a2 + a3);
}

// CHAMPION STRUCTURE (R14, ~101-103 us kernel): 256 blocks x 512 threads
// (8 waves, 2/SIMD), 4 batch rows per block, 1 block/CU.
// Transposed recurrence z^T = W_hh * h^T; wave w owns z-cols [16w,16w+16).
// MFMA n-dim (16) aliases the 4 real rows 4x (broadcast reads, free); only
// r16<4 lanes write h. Seed staging is software-pipelined: global embW loads
// for chunk k+1 issue into registers right after chunk k's boundary barrier
// and drain ~1000 cyc later at a step barrier (L2 latency fully hidden);
// the boundary itself only writes regs->ring. All in-loop traffic is
// conflict-free LDS (24K total conflicts measured).
//
// EIGHTEEN structural variants across two sessions all regressed:
// waves(4/8), rows/block, cg-pairing (R17: 1/SIMD exposes chain, +175cyc),
// VMEM seeds spread (R19: +8 in-loop VMEM, +55cyc) / burst (R21: +220cyc),
// dual-problem ILP (R20: phases serialize, 2x burst), co-residency,
// barrier-free, lgkm-only barrier + MFMA-split + capture-move micro-opts
// (R22: +115cyc codegen perturbation), wave-local no-barrier (R24: 1/SIMD
// occupancy ceiling is structural -- 1024 independent rows = max 1 wave/SIMD;
// +8x redundant MFMA issue; 1220cyc/step).
//
// Ceiling arithmetic: wall = longest row (256 serial steps) x step time.
// step = DS-burst (48 conflict-free ops x ~10cyc, per-CU pipe) + cross-wave
// h round-trip tail (~470cyc: ds_read ~120 -> 2-deep MFMA -> tanh -> pack ->
// write -> barrier) ~= 950cyc. 256 x 950 / 2.4GHz = 101us = measured.
// Counters at floor: MfmaUtil ~10%, VALUBusy ~31%, HBM ~0.16% -- no HW pipe
// near limit; the bound is serial dependence x per-step latency, with every
// reduction mechanism in the neighborhood measured and falsified.
__global__ void __launch_bounds__(512)
rnn_mfma(const int* __restrict__ x, const int* __restrict__ lengths,
         const float* __restrict__ embW, const float* __restrict__ W_hh,
         const float* __restrict__ W_fc, const float* __restrict__ b_fc,
         float* __restrict__ out) {
    const int tid = threadIdx.x;
    const int wave = tid >> 6;   // 0..7
    const int lane = tid & 63;
    const int q = lane >> 4;     // 0..3
    const int r16 = lane & 15;   // MFMA n index
    const int r4 = r16 & 3;      // real batch row (aliased 4x)
    const int c0 = wave * 16;    // wave's 16 z-cols
    const int b0 = blockIdx.x * ROWS;

    __shared__ __align__(16) float ring[CHUNK][ROWS][RSTR];   // 34816 B
    __shared__ __align__(16) _Float16 Ah[2][ROWS][ASTRIDE];   // 2304 B
    __shared__ int xs[ROWS][SEQ + 1];                         // 4112 B
    __shared__ __align__(16) float hfin[ROWS][HIDDEN];        // 2048 B
    __shared__ int lenbuf[ROWS];

    // Stage tokens + lengths; zero both h buffers.
    for (int idx = tid; idx < ROWS * SEQ; idx += 512) {
        int r = idx >> 8, t = idx & (SEQ - 1);
        xs[r][t] = x[(b0 + r) * SEQ + t];
    }
    if (tid < ROWS) lenbuf[tid] = lengths[b0 + tid];
    for (int idx = tid; idx < (int)(sizeof(Ah) / 4); idx += 512)
        ((int*)Ah)[idx] = 0;

    // Static A-frags of W_hh for this wave's 16-col slice:
    // A[m=r16][k=kc*32+q*8+j] = W_hh[c0 + r16][kc*32 + q*8 + j]. 16 VGPRs.
    f16x8 Wf[4];
    {
        const float* wrow = W_hh + (c0 + r16) * HIDDEN + q * 8;
#pragma unroll
        for (int kc = 0; kc < 4; ++kc) {
            const float* p = wrow + kc * 32;
#pragma unroll
            for (int j = 0; j < 8; ++j) Wf[kc][j] = (_Float16)p[j];
        }
    }

    __syncthreads();  // xs / lenbuf / Ah visible

    const int mylen = lenbuf[r4];
    int lenmax = 0;
#pragma unroll
    for (int r = 0; r < ROWS; ++r) lenmax = max(lenmax, lenbuf[r]);

    // Staging-thread mapping: idx = tid + 512k -> (tp, r, c4).
    const int s_c4 = tid & 31;
    const int s_r = (tid >> 5) & 3;
    const int s_tp = tid >> 7;   // 0..3, +4 per k

    // Prefetch chunk 0 seeds into registers.
    f32x4 rg[4];
#pragma unroll
    for (int k = 0; k < 4; ++k) {
        int tp = s_tp + 4 * k;
        int tok = xs[s_r][tp];
        rg[k] = *(const f32x4*)(embW + tok * HIDDEN + s_c4 * 4);
    }

    int cur = 0;
    f32x4 cap = {0.f, 0.f, 0.f, 0.f};

    for (int t0 = 0; t0 < lenmax; t0 += CHUNK) {
        // Boundary: staged regs -> ring (LDS only, cheap), then barrier.
#pragma unroll
        for (int k = 0; k < 4; ++k)
            *(f32x4*)&ring[s_tp + 4 * k][s_r][s_c4 * 4] = rg[k];
        __syncthreads();

        // Issue next chunk's global loads now; they complete during the
        // first couple of steps and drain harmlessly at a step barrier.
        if (t0 + CHUNK < lenmax) {
            const int t0n = t0 + CHUNK;
#pragma unroll
            for (int k = 0; k < 4; ++k) {
                int tp = s_tp + 4 * k;
                int tok = xs[s_r][t0n + tp];
                rg[k] = *(const f32x4*)(embW + tok * HIDDEN + s_c4 * 4);
            }
        }

        const int tend = (lenmax - t0 < CHUNK) ? lenmax - t0 : CHUNK;
        for (int tt = 0; tt < tend; ++tt) {
            // h B-frags: B[k][n=r16] = h[r4][k] (4-way broadcast, conflict-free).
            const _Float16* hb = &Ah[cur][r4][q * 8];
            f16x8 H0 = *(const f16x8*)(hb + 0);
            f16x8 H1 = *(const f16x8*)(hb + 32);
            f16x8 H2 = *(const f16x8*)(hb + 64);
            f16x8 H3 = *(const f16x8*)(hb + 96);

            // Seed: one conflict-free b128 from the ring, feeds C directly.
            f32x4 a = *(const f32x4*)&ring[tt][r4][c0 + 4 * q];
            f32x4 d = {0.f, 0.f, 0.f, 0.f};
            a = __builtin_amdgcn_mfma_f32_16x16x32_f16(Wf[0], H0, a, 0, 0, 0);
            d = __builtin_amdgcn_mfma_f32_16x16x32_f16(Wf[2], H2, d, 0, 0, 0);
            a = __builtin_amdgcn_mfma_f32_16x16x32_f16(Wf[1], H1, a, 0, 0, 0);
            d = __builtin_amdgcn_mfma_f32_16x16x32_f16(Wf[3], H3, d, 0, 0, 0);
            f32x4 z = a + d;

            f32x4 th;
            th[0] = fast_tanh(z[0]);
            th[1] = fast_tanh(z[1]);
            th[2] = fast_tanh(z[2]);
            th[3] = fast_tanh(z[3]);

            uint2 pk;
            pk.x = __builtin_bit_cast(unsigned int, __builtin_amdgcn_cvt_pkrtz(th[0], th[1]));
            pk.y = __builtin_bit_cast(unsigned int, __builtin_amdgcn_cvt_pkrtz(th[2], th[3]));

            const int nxt = cur ^ 1;
            if (r16 < ROWS)  // one writer per (row, col-quad)
                *(uint2*)&Ah[nxt][r16][c0 + 4 * q] = pk;
            // Capture off the critical path (after the write).
            if (t0 + tt + 1 == mylen) cap = th;
            __syncthreads();
            cur = nxt;
        }
    }

    // Final h (fp32 captures) -> hfin, then FC epilogue.
    if (r16 < ROWS)
        *(f32x4*)&hfin[r16][c0 + 4 * q] = cap;
    __syncthreads();

    // FC: thread (r, c) computes out[b0+r][c].  512 = 4 rows x 128 slots.
    const int r = tid >> 7;      // 0..3
    const int c = tid & 127;     // 0..127
    if (c < VOCAB) {
        const float4* hv = (const float4*)hfin[r];
        const float4* wf = (const float4*)(W_fc + c * HIDDEN);
        float a0 = 0.f, a1 = 0.f, a2 = 0.f, a3 = 0.f;
#pragma unroll
        for (int j = 0; j < HIDDEN / 4; ++j) {
            float4 h = hv[j];
            float4 w = wf[j];
            a0 += h.x * w.x; a1 += h.y * w.y; a2 += h.z * w.z; a3 += h.w * w.w;
        }
        out[(b0 + r) * VOCAB + c] = (a0 + a1) + (a2 + a3) + b_fc[c];
    }
}

extern "C" void kernel_launch(void* const* d_in, const int* in_sizes, int n_in,
                              void* d_out, int out_size, void* d_ws, size_t ws_size,
                              hipStream_t stream) {
    const int* x = (const int*)d_in[0];          // [B, T] int32
    const int* lengths = (const int*)d_in[1];    // [B] int32
    const float* emb = (const float*)d_in[2];    // [V, H]
    const float* W_ih = (const float*)d_in[3];   // [H, H]
    const float* W_hh = (const float*)d_in[4];   // [H, H]
    const float* W_fc = (const float*)d_in[5];   // [V, H]
    const float* b_fc = (const float*)d_in[6];   // [V]
    float* out = (float*)d_out;                  // [B, V]

    float* embW = (float*)d_ws;                  // VOCAB*HIDDEN floats (30 KB)

    rnn_prep_embw<<<VOCAB, HIDDEN, 0, stream>>>(emb, W_ih, embW);
    rnn_mfma<<<BATCH / ROWS, 512, 0, stream>>>(x, lengths, embW, W_hh, W_fc, b_fc, out);
}